// Round 4
// baseline (206.632 us; speedup 1.0000x reference)
//
#include <hip/hip_runtime.h>
#include <math.h>

#define EPS 1e-5f
#define B 64
#define N 1024
#define W 64
#define R 4
#define NW 1
#define LROWS 16   // rows per block in k_link

typedef float f4 __attribute__((ext_vector_type(4)));

__device__ __forceinline__ float softplus_f(float x) {
    return x > 0.f ? x + log1pf(expf(-x)) : log1pf(expf(x));
}

// Block-wide reduction over 1024 threads (16 waves). sred: 16 floats.
template <bool IS_MAX>
__device__ __forceinline__ float block_reduce(float v, float* sred) {
    #pragma unroll
    for (int off = 32; off >= 1; off >>= 1) {
        float o = __shfl_xor(v, off);
        v = IS_MAX ? fmaxf(v, o) : v + o;
    }
    __syncthreads();                    // protect sred reuse across calls
    if ((threadIdx.x & 63) == 0) sred[threadIdx.x >> 6] = v;
    __syncthreads();
    float r = sred[0];
    #pragma unroll
    for (int i = 1; i < 16; ++i) r = IS_MAX ? fmaxf(r, sred[i]) : r + sred[i];
    return r;
}

// ---- prep1: usage + sharpened cosine acts (one memory pass). grid (4,B)x256
__global__ __launch_bounds__(256) void k_prep1(
    const float* __restrict__ memory,
    const float* __restrict__ read_keys,
    const float* __restrict__ read_strengths,
    const float* __restrict__ write_keys,
    const float* __restrict__ write_strengths,
    const float* __restrict__ free_gate,
    const float* __restrict__ prev_read_w,
    const float* __restrict__ prev_write_w,
    const float* __restrict__ prev_usage,
    float* __restrict__ out_usage,
    float* __restrict__ out_rw,    // [B,R,N] sharpened acts (pre-softmax)
    float* __restrict__ out_ww) {  // [B,N]   sharpened acts (pre-softmax)
    __shared__ float sk[5 * W];
    __shared__ float s_knorm[5];
    __shared__ float s_scale[5];
    int b = blockIdx.y;
    int t = threadIdx.x;
    int n = blockIdx.x * 256 + t;

    for (int l = t; l < 5 * W; l += 256) {
        int h = l >> 6, w = l & 63;
        sk[l] = (h < R) ? read_keys[((size_t)b * R + h) * W + w]
                        : write_keys[(size_t)b * W + w];
    }
    __syncthreads();
    if (t < 5) {
        float s = 0.f;
        for (int w = 0; w < W; ++w) s += sk[t * W + w] * sk[t * W + w];
        s_knorm[t] = sqrtf(s + EPS);
        float st = (t < R) ? read_strengths[b * R + t] : write_strengths[b];
        s_scale[t] = softplus_f(st);
    }

    // usage (independent of keys; overlaps the key-norm work)
    float ww = prev_write_w[(size_t)b * N + n];     // NW == 1
    float pun = prev_usage[(size_t)b * N + n];
    float u = pun + (1.f - pun) * ww;
    float phi = 1.f;
    #pragma unroll
    for (int r = 0; r < R; ++r)
        phi *= 1.f - free_gate[b * R + r] * prev_read_w[((size_t)b * R + r) * N + n];
    out_usage[(size_t)b * N + n] = u * phi;

    __syncthreads();

    const f4* mrow = (const f4*)(memory + ((size_t)b * N + n) * W);
    float dot[5] = {0.f, 0.f, 0.f, 0.f, 0.f};
    float msum = 0.f;
    #pragma unroll
    for (int w4 = 0; w4 < W / 4; ++w4) {
        f4 m = mrow[w4];
        msum += m.x * m.x + m.y * m.y + m.z * m.z + m.w * m.w;
        #pragma unroll
        for (int h = 0; h < 5; ++h)
            dot[h] += sk[h * W + w4 * 4 + 0] * m.x + sk[h * W + w4 * 4 + 1] * m.y
                    + sk[h * W + w4 * 4 + 2] * m.z + sk[h * W + w4 * 4 + 3] * m.w;
    }
    float mnorm = sqrtf(msum + EPS);
    #pragma unroll
    for (int h = 0; h < 5; ++h) {
        float sharp = (dot[h] / (s_knorm[h] * mnorm + EPS)) * s_scale[h];
        if (h < R) out_rw[((size_t)b * R + h) * N + n] = sharp;
        else       out_ww[(size_t)b * N + n] = sharp;
    }
}

// ---- prep2: softmax(5 heads) + rank-product alloc + ww + precedence ----
// One block of 1024 threads per batch; thread t owns slot n = t.
__global__ __launch_bounds__(1024) void k_prep2(
    float* __restrict__ out_rw,          // acts in, softmax out
    float* __restrict__ out_ww,          // acts in, final ww out
    const float* __restrict__ usage,
    const float* __restrict__ alloc_gate,
    const float* __restrict__ write_gate,
    const float* __restrict__ prev_prec,
    float* __restrict__ out_prec) {
    __shared__ float su[N];
    __shared__ float sred[16];
    int b = blockIdx.x;
    int t = threadIdx.x;

    // stage usage for the rank-product
    float ui = EPS + (1.f - EPS) * usage[(size_t)b * N + t];
    su[t] = ui;

    // softmax per head (block-wide shuffle+LDS reduce)
    float content = 0.f;
    #pragma unroll
    for (int h = 0; h < 5; ++h) {
        float a = (h < R) ? out_rw[((size_t)b * R + h) * N + t]
                          : out_ww[(size_t)b * N + t];
        float mx = block_reduce<true>(a, sred);
        float e = expf(a - mx);
        float sm = block_reduce<false>(e, sred);
        float p = e / sm;
        if (h < R) out_rw[((size_t)b * R + h) * N + t] = p;
        else       content = p;
    }
    __syncthreads();   // su fully written, sred traffic done

    // alloc_t = (1-uu_t) * prod{ uu_j : uu_j < uu_t || (uu_j==uu_t && j<t) }
    float prod = 1.f;
    for (int j4 = 0; j4 < N / 4; ++j4) {
        f4 v = ((const f4*)su)[j4];   // uniform addr -> LDS broadcast
        int j = 4 * j4;
        prod *= ((v.x < ui) || (v.x == ui && (j + 0) < t)) ? v.x : 1.f;
        prod *= ((v.y < ui) || (v.y == ui && (j + 1) < t)) ? v.y : 1.f;
        prod *= ((v.z < ui) || (v.z == ui && (j + 2) < t)) ? v.z : 1.f;
        prod *= ((v.w < ui) || (v.w == ui && (j + 3) < t)) ? v.w : 1.f;
    }
    float alloc = (1.f - ui) * prod;

    // final write weights + precedence
    float ag = alloc_gate[b], wg = write_gate[b];
    float w = wg * (ag * alloc + (1.f - ag) * content);
    float wsum = block_reduce<false>(w, sred);
    out_ww[(size_t)b * N + t] = w;
    out_prec[(size_t)b * N + t] = (1.f - wsum) * prev_prec[(size_t)b * N + t] + w;
}

// ---- link update: 16 rows/block, wj/pj register-cached, plain loads ----
__global__ __launch_bounds__(256) void k_link(const float* __restrict__ ww,
                                              const float* __restrict__ pprec,
                                              const float* __restrict__ plink,
                                              float* __restrict__ link) {
    int row0 = blockIdx.x * LROWS;       // 1024 % 16 == 0 -> one batch
    int b = row0 >> 10;
    int t = threadIdx.x;                 // j-chunk: j in [4t, 4t+4)

    f4 wj = ((const f4*)(ww + (size_t)b * N))[t];
    f4 pj = ((const f4*)(pprec + (size_t)b * N))[t];

    for (int r0 = 0; r0 < LROWS; r0 += 4) {
        float wi[4];
        f4 pl[4];
        #pragma unroll
        for (int k = 0; k < 4; ++k) {
            int row = row0 + r0 + k;
            wi[k] = ww[row];
            pl[k] = ((const f4*)plink)[((size_t)row << 8) + t];
        }
        #pragma unroll
        for (int k = 0; k < 4; ++k) {
            int row = row0 + r0 + k;
            int i = row & (N - 1);
            f4 a = (1.f - wi[k]) - wj;
            f4 o = a * pl[k] + wi[k] * pj;
            if ((i >> 2) == t) {         // zero the diagonal element
                int jj = i & 3;
                if      (jj == 0) o.x = 0.f;
                else if (jj == 1) o.y = 0.f;
                else if (jj == 2) o.z = 0.f;
                else              o.w = 0.f;
            }
            ((f4*)link)[((size_t)row << 8) + t] = o;
        }
    }
}

extern "C" void kernel_launch(void* const* d_in, const int* in_sizes, int n_in,
                              void* d_out, int out_size, void* d_ws, size_t ws_size,
                              hipStream_t stream) {
    const float* memory          = (const float*)d_in[0];
    const float* read_keys       = (const float*)d_in[1];
    const float* read_strengths  = (const float*)d_in[2];
    const float* write_keys      = (const float*)d_in[3];
    const float* write_strengths = (const float*)d_in[4];
    const float* free_gate       = (const float*)d_in[5];
    const float* alloc_gate      = (const float*)d_in[6];
    const float* write_gate      = (const float*)d_in[7];
    const float* prev_read_w     = (const float*)d_in[8];
    const float* prev_write_w    = (const float*)d_in[9];
    const float* prev_usage      = (const float*)d_in[10];
    const float* prev_link       = (const float*)d_in[11];
    const float* prev_prec       = (const float*)d_in[12];

    float* out = (float*)d_out;
    float* out_rw    = out;                               // [B,R,N]
    float* out_ww    = out_rw + (size_t)B * R * N;        // [B,NW,N]
    float* out_usage = out_ww + (size_t)B * NW * N;       // [B,N]
    float* out_link  = out_usage + (size_t)B * N;         // [B,NW,N,N]
    float* out_prec  = out_link + (size_t)B * NW * N * N; // [B,NW,N]

    dim3 g1(N / 256, B);
    k_prep1<<<g1, 256, 0, stream>>>(memory, read_keys, read_strengths,
                                    write_keys, write_strengths, free_gate,
                                    prev_read_w, prev_write_w, prev_usage,
                                    out_usage, out_rw, out_ww);

    k_prep2<<<B, 1024, 0, stream>>>(out_rw, out_ww, out_usage,
                                    alloc_gate, write_gate, prev_prec, out_prec);

    k_link<<<(B * N) / LROWS, 256, 0, stream>>>(out_ww, prev_prec,
                                                prev_link, out_link);
}

// Round 5
// 135.291 us; speedup vs baseline: 1.5273x; 1.5273x over previous
//
#include <hip/hip_runtime.h>
#include <math.h>

#define EPS 1e-5f
#define B 64
#define N 1024
#define W 64
#define R 4
#define NW 1

__device__ __forceinline__ float softplus_f(float x) {
    return x > 0.f ? x + log1pf(expf(-x)) : log1pf(expf(x));
}

// -------------------- usage --------------------
__global__ void k_usage(const float* __restrict__ pww,
                        const float* __restrict__ fg,
                        const float* __restrict__ prw,
                        const float* __restrict__ pu,
                        float* __restrict__ usage) {
    int idx = blockIdx.x * blockDim.x + threadIdx.x;  // over B*N
    if (idx >= B * N) return;
    int b = idx >> 10;
    int n = idx & (N - 1);
    float wwp = 1.f;
    for (int h = 0; h < NW; ++h)
        wwp *= 1.f - pww[(b * NW + h) * N + n];
    float ww = 1.f - wwp;
    float pun = pu[idx];
    float u = pun + (1.f - pun) * ww;
    float phi = 1.f;
    for (int r = 0; r < R; ++r)
        phi *= 1.f - fg[b * R + r] * prw[(size_t)(b * R + r) * N + n];
    usage[idx] = u * phi;
}

// -------------------- allocation (sort per batch) --------------------
__global__ __launch_bounds__(1024) void k_alloc(const float* __restrict__ usage,
                                                float* __restrict__ alloc) {
    __shared__ float nu[N];
    __shared__ int   id[N];
    __shared__ float pp[N];
    int b = blockIdx.x;
    int t = threadIdx.x;

    float u = EPS + (1.f - EPS) * usage[(size_t)b * N + t];
    nu[t] = 1.f - u;   // nonusage
    id[t] = t;
    __syncthreads();

    // Bitonic sort: descending nonusage, ties broken by ascending original
    // index (matches stable jnp.argsort(-nonusage)).
    for (int k = 2; k <= N; k <<= 1) {
        for (int j = k >> 1; j > 0; j >>= 1) {
            int ixj = t ^ j;
            if (ixj > t) {
                float na = nu[t], nb = nu[ixj];
                int   ia = id[t], ib = id[ixj];
                bool a_first = (na > nb) || (na == nb && ia < ib);
                bool up = ((t & k) == 0);
                bool doSwap = up ? !a_first : a_first;
                if (doSwap) {
                    nu[t] = nb; nu[ixj] = na;
                    id[t] = ib; id[ixj] = ia;
                }
            }
            __syncthreads();
        }
    }

    // Inclusive prefix product of sorted_usage = 1 - sorted_nonusage.
    pp[t] = 1.f - nu[t];
    __syncthreads();
    for (int off = 1; off < N; off <<= 1) {
        float v = pp[t];
        float w = (t >= off) ? pp[t - off] : 1.f;
        __syncthreads();
        pp[t] = v * w;
        __syncthreads();
    }
    float excl = (t > 0) ? pp[t - 1] : 1.f;   // exclusive prefix product
    // Scatter: alloc[indices[k]] = sorted_alloc[k]
    alloc[(size_t)b * N + id[t]] = nu[t] * excl;
}

// -------------------- cosine scores (all 5 heads, one memory pass) ------
__global__ void k_scores(const float* __restrict__ memory,
                         const float* __restrict__ read_keys,
                         const float* __restrict__ read_strengths,
                         const float* __restrict__ write_keys,
                         const float* __restrict__ write_strengths,
                         float* __restrict__ out_rw,   // [B,R,N] sharpened acts
                         float* __restrict__ out_ww) { // [B,N] sharpened acts
    __shared__ float sk[5 * W];
    __shared__ float s_knorm[5];
    __shared__ float s_scale[5];
    int b = blockIdx.y;
    int t = threadIdx.x;   // 256

    for (int l = t; l < 5 * W; l += 256) {
        int h = l / W, w = l - h * W;
        sk[l] = (h < R) ? read_keys[((size_t)b * R + h) * W + w]
                        : write_keys[(size_t)b * W + w];
    }
    __syncthreads();
    if (t < 5) {
        float s = 0.f;
        for (int w = 0; w < W; ++w) s += sk[t * W + w] * sk[t * W + w];
        s_knorm[t] = sqrtf(s + EPS);
        float st = (t < R) ? read_strengths[b * R + t] : write_strengths[b];
        s_scale[t] = softplus_f(st);
    }
    __syncthreads();

    int n = blockIdx.x * 256 + t;
    const float4* mrow = (const float4*)(memory + ((size_t)b * N + n) * W);
    float dot[5] = {0.f, 0.f, 0.f, 0.f, 0.f};
    float msum = 0.f;
    for (int w4 = 0; w4 < W / 4; ++w4) {
        float4 m = mrow[w4];
        msum += m.x * m.x + m.y * m.y + m.z * m.z + m.w * m.w;
        for (int h = 0; h < 5; ++h) {
            dot[h] += sk[h * W + w4 * 4 + 0] * m.x + sk[h * W + w4 * 4 + 1] * m.y
                    + sk[h * W + w4 * 4 + 2] * m.z + sk[h * W + w4 * 4 + 3] * m.w;
        }
    }
    float mnorm = sqrtf(msum + EPS);
    for (int h = 0; h < 5; ++h) {
        float act = dot[h] / (s_knorm[h] * mnorm + EPS);
        float sharp = act * s_scale[h];
        if (h < R) out_rw[((size_t)b * R + h) * N + n] = sharp;
        else       out_ww[(size_t)b * N + n] = sharp;
    }
}

// -------------------- softmax over N, in place --------------------
__global__ void k_softmax(float* __restrict__ out_rw, float* __restrict__ out_ww) {
    int blk = blockIdx.x;     // B*5
    int b = blk / 5, h = blk - b * 5;
    float* p = (h < R) ? (out_rw + ((size_t)b * R + h) * N)
                       : (out_ww + (size_t)b * N);
    int t = threadIdx.x;      // 256
    float v[4];
    float mx = -INFINITY;
    for (int k = 0; k < 4; ++k) { v[k] = p[t + 256 * k]; mx = fmaxf(mx, v[k]); }
    __shared__ float red[256];
    red[t] = mx; __syncthreads();
    for (int s = 128; s > 0; s >>= 1) {
        if (t < s) red[t] = fmaxf(red[t], red[t + s]);
        __syncthreads();
    }
    mx = red[0]; __syncthreads();
    float sum = 0.f;
    for (int k = 0; k < 4; ++k) { v[k] = expf(v[k] - mx); sum += v[k]; }
    red[t] = sum; __syncthreads();
    for (int s = 128; s > 0; s >>= 1) {
        if (t < s) red[t] += red[t + s];
        __syncthreads();
    }
    float inv = 1.f / red[0];
    for (int k = 0; k < 4; ++k) p[t + 256 * k] = v[k] * inv;
}

// -------------------- final write weights + precedence --------------------
__global__ void k_wwprec(const float* __restrict__ alloc,
                         const float* __restrict__ alloc_gate,
                         const float* __restrict__ write_gate,
                         const float* __restrict__ prev_prec,
                         float* __restrict__ out_ww,   // in: content softmax, out: final ww
                         float* __restrict__ out_prec) {
    int b = blockIdx.x;
    int t = threadIdx.x;  // 256
    float ag = alloc_gate[b], wg = write_gate[b];
    float v[4];
    float sum = 0.f;
    for (int k = 0; k < 4; ++k) {
        int n = t + 256 * k;
        float c = out_ww[(size_t)b * N + n];
        float a = alloc[(size_t)b * N + n];
        float w = wg * (ag * a + (1.f - ag) * c);
        v[k] = w; sum += w;
    }
    __shared__ float red[256];
    red[t] = sum; __syncthreads();
    for (int s = 128; s > 0; s >>= 1) {
        if (t < s) red[t] += red[t + s];
        __syncthreads();
    }
    float wsum = red[0];
    for (int k = 0; k < 4; ++k) {
        int n = t + 256 * k;
        out_ww[(size_t)b * N + n] = v[k];
        out_prec[(size_t)b * N + n] = (1.f - wsum) * prev_prec[(size_t)b * N + n] + v[k];
    }
}

// -------------------- link update (the HBM-bound bulk) --------------------
__global__ void k_link(const float* __restrict__ ww,
                       const float* __restrict__ pprec,
                       const float* __restrict__ plink,
                       float* __restrict__ link) {
    int row = blockIdx.x;               // b*N + i
    int b = row >> 10, i = row & (N - 1);
    int t = threadIdx.x;                // 256 threads = 256 float4 = one row
    float wi = ww[row];
    size_t base4 = ((size_t)row << 10) >> 2;   // row*N/4 in float4 units
    float4 pl = ((const float4*)plink)[base4 + t];
    float4 wj = ((const float4*)(ww + (size_t)b * N))[t];
    float4 pj = ((const float4*)(pprec + (size_t)b * N))[t];
    float4 o;
    o.x = (1.f - wi - wj.x) * pl.x + wi * pj.x;
    o.y = (1.f - wi - wj.y) * pl.y + wi * pj.y;
    o.z = (1.f - wi - wj.z) * pl.z + wi * pj.z;
    o.w = (1.f - wi - wj.w) * pl.w + wi * pj.w;
    int j0 = t * 4;
    if (i >= j0 && i < j0 + 4) {       // zero the diagonal
        if      (i == j0)     o.x = 0.f;
        else if (i == j0 + 1) o.y = 0.f;
        else if (i == j0 + 2) o.z = 0.f;
        else                  o.w = 0.f;
    }
    ((float4*)link)[base4 + t] = o;
}

extern "C" void kernel_launch(void* const* d_in, const int* in_sizes, int n_in,
                              void* d_out, int out_size, void* d_ws, size_t ws_size,
                              hipStream_t stream) {
    const float* memory          = (const float*)d_in[0];
    const float* read_keys       = (const float*)d_in[1];
    const float* read_strengths  = (const float*)d_in[2];
    const float* write_keys      = (const float*)d_in[3];
    const float* write_strengths = (const float*)d_in[4];
    const float* free_gate       = (const float*)d_in[5];
    const float* alloc_gate      = (const float*)d_in[6];
    const float* write_gate      = (const float*)d_in[7];
    const float* prev_read_w     = (const float*)d_in[8];
    const float* prev_write_w    = (const float*)d_in[9];
    const float* prev_usage      = (const float*)d_in[10];
    const float* prev_link       = (const float*)d_in[11];
    const float* prev_prec       = (const float*)d_in[12];

    float* out = (float*)d_out;
    float* out_rw    = out;                           // [B,R,N]
    float* out_ww    = out_rw + (size_t)B * R * N;    // [B,NW,N]
    float* out_usage = out_ww + (size_t)B * NW * N;   // [B,N]
    float* out_link  = out_usage + (size_t)B * N;     // [B,NW,N,N]
    float* out_prec  = out_link + (size_t)B * NW * N * N; // [B,NW,N]

    // alloc scratch lives in the first B*N floats of out_link; k_link fully
    // overwrites that region afterwards, so this is race-free & deterministic.
    float* alloc_buf = out_link;

    k_usage<<<(B * N + 255) / 256, 256, 0, stream>>>(
        prev_write_w, free_gate, prev_read_w, prev_usage, out_usage);

    k_alloc<<<B, 1024, 0, stream>>>(out_usage, alloc_buf);

    dim3 g3(N / 256, B);
    k_scores<<<g3, 256, 0, stream>>>(memory, read_keys, read_strengths,
                                     write_keys, write_strengths, out_rw, out_ww);

    k_softmax<<<B * 5, 256, 0, stream>>>(out_rw, out_ww);

    k_wwprec<<<B, 256, 0, stream>>>(alloc_buf, alloc_gate, write_gate,
                                    prev_prec, out_ww, out_prec);

    k_link<<<B * N, 256, 0, stream>>>(out_ww, prev_prec, prev_link, out_link);
}

// Round 6
// 134.881 us; speedup vs baseline: 1.5320x; 1.0030x over previous
//
#include <hip/hip_runtime.h>
#include <math.h>

#define EPS 1e-5f
#define B 64
#define N 1024
#define W 64
#define R 4
#define NW 1
#define RPB 4   // rows per block in k_link (the single change vs R5)

__device__ __forceinline__ float softplus_f(float x) {
    return x > 0.f ? x + log1pf(expf(-x)) : log1pf(expf(x));
}

// -------------------- usage --------------------
__global__ void k_usage(const float* __restrict__ pww,
                        const float* __restrict__ fg,
                        const float* __restrict__ prw,
                        const float* __restrict__ pu,
                        float* __restrict__ usage) {
    int idx = blockIdx.x * blockDim.x + threadIdx.x;  // over B*N
    if (idx >= B * N) return;
    int b = idx >> 10;
    int n = idx & (N - 1);
    float wwp = 1.f;
    for (int h = 0; h < NW; ++h)
        wwp *= 1.f - pww[(b * NW + h) * N + n];
    float ww = 1.f - wwp;
    float pun = pu[idx];
    float u = pun + (1.f - pun) * ww;
    float phi = 1.f;
    for (int r = 0; r < R; ++r)
        phi *= 1.f - fg[b * R + r] * prw[(size_t)(b * R + r) * N + n];
    usage[idx] = u * phi;
}

// -------------------- allocation (sort per batch) --------------------
__global__ __launch_bounds__(1024) void k_alloc(const float* __restrict__ usage,
                                                float* __restrict__ alloc) {
    __shared__ float nu[N];
    __shared__ int   id[N];
    __shared__ float pp[N];
    int b = blockIdx.x;
    int t = threadIdx.x;

    float u = EPS + (1.f - EPS) * usage[(size_t)b * N + t];
    nu[t] = 1.f - u;   // nonusage
    id[t] = t;
    __syncthreads();

    // Bitonic sort: descending nonusage, ties broken by ascending original
    // index (matches stable jnp.argsort(-nonusage)).
    for (int k = 2; k <= N; k <<= 1) {
        for (int j = k >> 1; j > 0; j >>= 1) {
            int ixj = t ^ j;
            if (ixj > t) {
                float na = nu[t], nb = nu[ixj];
                int   ia = id[t], ib = id[ixj];
                bool a_first = (na > nb) || (na == nb && ia < ib);
                bool up = ((t & k) == 0);
                bool doSwap = up ? !a_first : a_first;
                if (doSwap) {
                    nu[t] = nb; nu[ixj] = na;
                    id[t] = ib; id[ixj] = ia;
                }
            }
            __syncthreads();
        }
    }

    // Inclusive prefix product of sorted_usage = 1 - sorted_nonusage.
    pp[t] = 1.f - nu[t];
    __syncthreads();
    for (int off = 1; off < N; off <<= 1) {
        float v = pp[t];
        float w = (t >= off) ? pp[t - off] : 1.f;
        __syncthreads();
        pp[t] = v * w;
        __syncthreads();
    }
    float excl = (t > 0) ? pp[t - 1] : 1.f;   // exclusive prefix product
    // Scatter: alloc[indices[k]] = sorted_alloc[k]
    alloc[(size_t)b * N + id[t]] = nu[t] * excl;
}

// -------------------- cosine scores (all 5 heads, one memory pass) ------
__global__ void k_scores(const float* __restrict__ memory,
                         const float* __restrict__ read_keys,
                         const float* __restrict__ read_strengths,
                         const float* __restrict__ write_keys,
                         const float* __restrict__ write_strengths,
                         float* __restrict__ out_rw,   // [B,R,N] sharpened acts
                         float* __restrict__ out_ww) { // [B,N] sharpened acts
    __shared__ float sk[5 * W];
    __shared__ float s_knorm[5];
    __shared__ float s_scale[5];
    int b = blockIdx.y;
    int t = threadIdx.x;   // 256

    for (int l = t; l < 5 * W; l += 256) {
        int h = l / W, w = l - h * W;
        sk[l] = (h < R) ? read_keys[((size_t)b * R + h) * W + w]
                        : write_keys[(size_t)b * W + w];
    }
    __syncthreads();
    if (t < 5) {
        float s = 0.f;
        for (int w = 0; w < W; ++w) s += sk[t * W + w] * sk[t * W + w];
        s_knorm[t] = sqrtf(s + EPS);
        float st = (t < R) ? read_strengths[b * R + t] : write_strengths[b];
        s_scale[t] = softplus_f(st);
    }
    __syncthreads();

    int n = blockIdx.x * 256 + t;
    const float4* mrow = (const float4*)(memory + ((size_t)b * N + n) * W);
    float dot[5] = {0.f, 0.f, 0.f, 0.f, 0.f};
    float msum = 0.f;
    for (int w4 = 0; w4 < W / 4; ++w4) {
        float4 m = mrow[w4];
        msum += m.x * m.x + m.y * m.y + m.z * m.z + m.w * m.w;
        for (int h = 0; h < 5; ++h) {
            dot[h] += sk[h * W + w4 * 4 + 0] * m.x + sk[h * W + w4 * 4 + 1] * m.y
                    + sk[h * W + w4 * 4 + 2] * m.z + sk[h * W + w4 * 4 + 3] * m.w;
        }
    }
    float mnorm = sqrtf(msum + EPS);
    for (int h = 0; h < 5; ++h) {
        float act = dot[h] / (s_knorm[h] * mnorm + EPS);
        float sharp = act * s_scale[h];
        if (h < R) out_rw[((size_t)b * R + h) * N + n] = sharp;
        else       out_ww[(size_t)b * N + n] = sharp;
    }
}

// -------------------- softmax over N, in place --------------------
__global__ void k_softmax(float* __restrict__ out_rw, float* __restrict__ out_ww) {
    int blk = blockIdx.x;     // B*5
    int b = blk / 5, h = blk - b * 5;
    float* p = (h < R) ? (out_rw + ((size_t)b * R + h) * N)
                       : (out_ww + (size_t)b * N);
    int t = threadIdx.x;      // 256
    float v[4];
    float mx = -INFINITY;
    for (int k = 0; k < 4; ++k) { v[k] = p[t + 256 * k]; mx = fmaxf(mx, v[k]); }
    __shared__ float red[256];
    red[t] = mx; __syncthreads();
    for (int s = 128; s > 0; s >>= 1) {
        if (t < s) red[t] = fmaxf(red[t], red[t + s]);
        __syncthreads();
    }
    mx = red[0]; __syncthreads();
    float sum = 0.f;
    for (int k = 0; k < 4; ++k) { v[k] = expf(v[k] - mx); sum += v[k]; }
    red[t] = sum; __syncthreads();
    for (int s = 128; s > 0; s >>= 1) {
        if (t < s) red[t] += red[t + s];
        __syncthreads();
    }
    float inv = 1.f / red[0];
    for (int k = 0; k < 4; ++k) p[t + 256 * k] = v[k] * inv;
}

// -------------------- final write weights + precedence --------------------
__global__ void k_wwprec(const float* __restrict__ alloc,
                         const float* __restrict__ alloc_gate,
                         const float* __restrict__ write_gate,
                         const float* __restrict__ prev_prec,
                         float* __restrict__ out_ww,   // in: content softmax, out: final ww
                         float* __restrict__ out_prec) {
    int b = blockIdx.x;
    int t = threadIdx.x;  // 256
    float ag = alloc_gate[b], wg = write_gate[b];
    float v[4];
    float sum = 0.f;
    for (int k = 0; k < 4; ++k) {
        int n = t + 256 * k;
        float c = out_ww[(size_t)b * N + n];
        float a = alloc[(size_t)b * N + n];
        float w = wg * (ag * a + (1.f - ag) * c);
        v[k] = w; sum += w;
    }
    __shared__ float red[256];
    red[t] = sum; __syncthreads();
    for (int s = 128; s > 0; s >>= 1) {
        if (t < s) red[t] += red[t + s];
        __syncthreads();
    }
    float wsum = red[0];
    for (int k = 0; k < 4; ++k) {
        int n = t + 256 * k;
        out_ww[(size_t)b * N + n] = v[k];
        out_prec[(size_t)b * N + n] = (1.f - wsum) * prev_prec[(size_t)b * N + n] + v[k];
    }
}

// ---- link update: RPB rows per block, wj/pj loaded once, plain loads ----
__global__ void k_link(const float* __restrict__ ww,
                       const float* __restrict__ pprec,
                       const float* __restrict__ plink,
                       float* __restrict__ link) {
    int row0 = blockIdx.x * RPB;        // 1024 % RPB == 0 -> one batch per block
    int b = row0 >> 10;
    int t = threadIdx.x;                // j-chunk: j in [4t, 4t+4)

    float4 wj = ((const float4*)(ww + (size_t)b * N))[t];
    float4 pj = ((const float4*)(pprec + (size_t)b * N))[t];

    float  wi[RPB];
    float4 pl[RPB];
    #pragma unroll
    for (int r = 0; r < RPB; ++r) {
        int row = row0 + r;
        wi[r] = ww[row];
        pl[r] = ((const float4*)plink)[((size_t)row << 8) + t];
    }

    #pragma unroll
    for (int r = 0; r < RPB; ++r) {
        int row = row0 + r;
        int i = row & (N - 1);
        float4 o;
        o.x = (1.f - wi[r] - wj.x) * pl[r].x + wi[r] * pj.x;
        o.y = (1.f - wi[r] - wj.y) * pl[r].y + wi[r] * pj.y;
        o.z = (1.f - wi[r] - wj.z) * pl[r].z + wi[r] * pj.z;
        o.w = (1.f - wi[r] - wj.w) * pl[r].w + wi[r] * pj.w;
        if ((i >> 2) == t) {            // zero the diagonal element
            int jj = i & 3;
            if      (jj == 0) o.x = 0.f;
            else if (jj == 1) o.y = 0.f;
            else if (jj == 2) o.z = 0.f;
            else              o.w = 0.f;
        }
        ((float4*)link)[((size_t)row << 8) + t] = o;
    }
}

extern "C" void kernel_launch(void* const* d_in, const int* in_sizes, int n_in,
                              void* d_out, int out_size, void* d_ws, size_t ws_size,
                              hipStream_t stream) {
    const float* memory          = (const float*)d_in[0];
    const float* read_keys       = (const float*)d_in[1];
    const float* read_strengths  = (const float*)d_in[2];
    const float* write_keys      = (const float*)d_in[3];
    const float* write_strengths = (const float*)d_in[4];
    const float* free_gate       = (const float*)d_in[5];
    const float* alloc_gate      = (const float*)d_in[6];
    const float* write_gate      = (const float*)d_in[7];
    const float* prev_read_w     = (const float*)d_in[8];
    const float* prev_write_w    = (const float*)d_in[9];
    const float* prev_usage      = (const float*)d_in[10];
    const float* prev_link       = (const float*)d_in[11];
    const float* prev_prec       = (const float*)d_in[12];

    float* out = (float*)d_out;
    float* out_rw    = out;                           // [B,R,N]
    float* out_ww    = out_rw + (size_t)B * R * N;    // [B,NW,N]
    float* out_usage = out_ww + (size_t)B * NW * N;   // [B,N]
    float* out_link  = out_usage + (size_t)B * N;     // [B,NW,N,N]
    float* out_prec  = out_link + (size_t)B * NW * N * N; // [B,NW,N]

    // alloc scratch lives in the first B*N floats of out_link; k_link fully
    // overwrites that region afterwards, so this is race-free & deterministic.
    float* alloc_buf = out_link;

    k_usage<<<(B * N + 255) / 256, 256, 0, stream>>>(
        prev_write_w, free_gate, prev_read_w, prev_usage, out_usage);

    k_alloc<<<B, 1024, 0, stream>>>(out_usage, alloc_buf);

    dim3 g3(N / 256, B);
    k_scores<<<g3, 256, 0, stream>>>(memory, read_keys, read_strengths,
                                     write_keys, write_strengths, out_rw, out_ww);

    k_softmax<<<B * 5, 256, 0, stream>>>(out_rw, out_ww);

    k_wwprec<<<B, 256, 0, stream>>>(alloc_buf, alloc_gate, write_gate,
                                    prev_prec, out_ww, out_prec);

    k_link<<<(B * N) / RPB, 256, 0, stream>>>(out_ww, prev_prec, prev_link, out_link);
}

// Round 7
// 121.830 us; speedup vs baseline: 1.6961x; 1.1071x over previous
//
#include <hip/hip_runtime.h>
#include <math.h>

#define EPS 1e-5f
#define B 64
#define N 1024
#define W 64
#define R 4
#define NW 1
#define RPB 4   // rows per block in k_link (R6-proven)

typedef float f4 __attribute__((ext_vector_type(4)));

__device__ __forceinline__ float softplus_f(float x) {
    return x > 0.f ? x + log1pf(expf(-x)) : log1pf(expf(x));
}

// Block-wide reduction over 1024 threads (16 waves). sred: 16 floats.
template <bool IS_MAX>
__device__ __forceinline__ float block_reduce(float v, float* sred) {
    #pragma unroll
    for (int off = 32; off >= 1; off >>= 1) {
        float o = __shfl_xor(v, off);
        v = IS_MAX ? fmaxf(v, o) : v + o;
    }
    __syncthreads();                    // protect sred reuse across calls
    if ((threadIdx.x & 63) == 0) sred[threadIdx.x >> 6] = v;
    __syncthreads();
    float r = sred[0];
    #pragma unroll
    for (int i = 1; i < 16; ++i) r = IS_MAX ? fmaxf(r, sred[i]) : r + sred[i];
    return r;
}

// ---- prep1: usage + sharpened cosine acts (one memory pass). grid (4,B)x256
// (verbatim from R4 — exonerated; R4's regression was the LROWS=16 link)
__global__ __launch_bounds__(256) void k_prep1(
    const float* __restrict__ memory,
    const float* __restrict__ read_keys,
    const float* __restrict__ read_strengths,
    const float* __restrict__ write_keys,
    const float* __restrict__ write_strengths,
    const float* __restrict__ free_gate,
    const float* __restrict__ prev_read_w,
    const float* __restrict__ prev_write_w,
    const float* __restrict__ prev_usage,
    float* __restrict__ out_usage,
    float* __restrict__ out_rw,    // [B,R,N] sharpened acts (pre-softmax)
    float* __restrict__ out_ww) {  // [B,N]   sharpened acts (pre-softmax)
    __shared__ float sk[5 * W];
    __shared__ float s_knorm[5];
    __shared__ float s_scale[5];
    int b = blockIdx.y;
    int t = threadIdx.x;
    int n = blockIdx.x * 256 + t;

    for (int l = t; l < 5 * W; l += 256) {
        int h = l >> 6, w = l & 63;
        sk[l] = (h < R) ? read_keys[((size_t)b * R + h) * W + w]
                        : write_keys[(size_t)b * W + w];
    }
    __syncthreads();
    if (t < 5) {
        float s = 0.f;
        for (int w = 0; w < W; ++w) s += sk[t * W + w] * sk[t * W + w];
        s_knorm[t] = sqrtf(s + EPS);
        float st = (t < R) ? read_strengths[b * R + t] : write_strengths[b];
        s_scale[t] = softplus_f(st);
    }

    // usage (independent of keys; overlaps the key-norm work)
    float ww = prev_write_w[(size_t)b * N + n];     // NW == 1
    float pun = prev_usage[(size_t)b * N + n];
    float u = pun + (1.f - pun) * ww;
    float phi = 1.f;
    #pragma unroll
    for (int r = 0; r < R; ++r)
        phi *= 1.f - free_gate[b * R + r] * prev_read_w[((size_t)b * R + r) * N + n];
    out_usage[(size_t)b * N + n] = u * phi;

    __syncthreads();

    const f4* mrow = (const f4*)(memory + ((size_t)b * N + n) * W);
    float dot[5] = {0.f, 0.f, 0.f, 0.f, 0.f};
    float msum = 0.f;
    #pragma unroll
    for (int w4 = 0; w4 < W / 4; ++w4) {
        f4 m = mrow[w4];
        msum += m.x * m.x + m.y * m.y + m.z * m.z + m.w * m.w;
        #pragma unroll
        for (int h = 0; h < 5; ++h)
            dot[h] += sk[h * W + w4 * 4 + 0] * m.x + sk[h * W + w4 * 4 + 1] * m.y
                    + sk[h * W + w4 * 4 + 2] * m.z + sk[h * W + w4 * 4 + 3] * m.w;
    }
    float mnorm = sqrtf(msum + EPS);
    #pragma unroll
    for (int h = 0; h < 5; ++h) {
        float sharp = (dot[h] / (s_knorm[h] * mnorm + EPS)) * s_scale[h];
        if (h < R) out_rw[((size_t)b * R + h) * N + n] = sharp;
        else       out_ww[(size_t)b * N + n] = sharp;
    }
}

// ---- alloc (R1's verbatim bitonic) + softmax(5) + ww + precedence ----
// One block of 1024 threads per batch; thread t owns slot n = t.
__global__ __launch_bounds__(1024) void k_allocsmww(
    const float* __restrict__ usage,
    float* __restrict__ out_rw,          // acts in, softmax out
    float* __restrict__ out_ww,          // acts in, final ww out
    const float* __restrict__ alloc_gate,
    const float* __restrict__ write_gate,
    const float* __restrict__ prev_prec,
    float* __restrict__ out_prec) {
    __shared__ float nu[N];
    __shared__ int   id[N];
    __shared__ float pp[N];
    __shared__ float sred[16];
    int b = blockIdx.x;
    int t = threadIdx.x;

    float u = EPS + (1.f - EPS) * usage[(size_t)b * N + t];
    nu[t] = 1.f - u;   // nonusage
    id[t] = t;
    __syncthreads();

    // Bitonic sort: descending nonusage, stable tie-break by index.
    for (int k = 2; k <= N; k <<= 1) {
        for (int j = k >> 1; j > 0; j >>= 1) {
            int ixj = t ^ j;
            if (ixj > t) {
                float na = nu[t], nb = nu[ixj];
                int   ia = id[t], ib = id[ixj];
                bool a_first = (na > nb) || (na == nb && ia < ib);
                bool up = ((t & k) == 0);
                bool doSwap = up ? !a_first : a_first;
                if (doSwap) {
                    nu[t] = nb; nu[ixj] = na;
                    id[t] = ib; id[ixj] = ia;
                }
            }
            __syncthreads();
        }
    }

    // Inclusive prefix product of sorted_usage = 1 - sorted_nonusage.
    pp[t] = 1.f - nu[t];
    __syncthreads();
    for (int off = 1; off < N; off <<= 1) {
        float v = pp[t];
        float w = (t >= off) ? pp[t - off] : 1.f;
        __syncthreads();
        pp[t] = v * w;
        __syncthreads();
    }
    float excl = (t > 0) ? pp[t - 1] : 1.f;
    float aval = nu[t] * excl;          // alloc for slot id[t]
    __syncthreads();                    // all pp reads done before reuse
    pp[id[t]] = aval;                   // scatter: pp becomes salloc
    __syncthreads();
    float alloc_t = pp[t];

    // softmax per head (block-wide shuffle+LDS reduce)
    float content = 0.f;
    #pragma unroll
    for (int h = 0; h < 5; ++h) {
        float a = (h < R) ? out_rw[((size_t)b * R + h) * N + t]
                          : out_ww[(size_t)b * N + t];
        float mx = block_reduce<true>(a, sred);
        float e = expf(a - mx);
        float sm = block_reduce<false>(e, sred);
        float p = e / sm;
        if (h < R) out_rw[((size_t)b * R + h) * N + t] = p;
        else       content = p;
    }

    // final write weights + precedence
    float ag = alloc_gate[b], wg = write_gate[b];
    float w = wg * (ag * alloc_t + (1.f - ag) * content);
    float wsum = block_reduce<false>(w, sred);
    out_ww[(size_t)b * N + t] = w;
    out_prec[(size_t)b * N + t] = (1.f - wsum) * prev_prec[(size_t)b * N + t] + w;
}

// ---- link update: RPB=4 rows/block (R6 anchor) + nontemporal streams ----
__global__ void k_link(const float* __restrict__ ww,
                       const float* __restrict__ pprec,
                       const float* __restrict__ plink,
                       float* __restrict__ link) {
    int row0 = blockIdx.x * RPB;        // 1024 % RPB == 0 -> one batch per block
    int b = row0 >> 10;
    int t = threadIdx.x;                // j-chunk: j in [4t, 4t+4)

    f4 wj = ((const f4*)(ww + (size_t)b * N))[t];
    f4 pj = ((const f4*)(pprec + (size_t)b * N))[t];

    float wi[RPB];
    f4    pl[RPB];
    #pragma unroll
    for (int r = 0; r < RPB; ++r) {
        int row = row0 + r;
        wi[r] = ww[row];
        pl[r] = __builtin_nontemporal_load((const f4*)plink + (((size_t)row) << 8) + t);
    }

    #pragma unroll
    for (int r = 0; r < RPB; ++r) {
        int row = row0 + r;
        int i = row & (N - 1);
        f4 a = (1.f - wi[r]) - wj;
        f4 o = a * pl[r] + wi[r] * pj;
        if ((i >> 2) == t) {            // zero the diagonal element
            int jj = i & 3;
            if      (jj == 0) o.x = 0.f;
            else if (jj == 1) o.y = 0.f;
            else if (jj == 2) o.z = 0.f;
            else              o.w = 0.f;
        }
        __builtin_nontemporal_store(o, (f4*)link + (((size_t)row) << 8) + t);
    }
}

extern "C" void kernel_launch(void* const* d_in, const int* in_sizes, int n_in,
                              void* d_out, int out_size, void* d_ws, size_t ws_size,
                              hipStream_t stream) {
    const float* memory          = (const float*)d_in[0];
    const float* read_keys       = (const float*)d_in[1];
    const float* read_strengths  = (const float*)d_in[2];
    const float* write_keys      = (const float*)d_in[3];
    const float* write_strengths = (const float*)d_in[4];
    const float* free_gate       = (const float*)d_in[5];
    const float* alloc_gate      = (const float*)d_in[6];
    const float* write_gate      = (const float*)d_in[7];
    const float* prev_read_w     = (const float*)d_in[8];
    const float* prev_write_w    = (const float*)d_in[9];
    const float* prev_usage      = (const float*)d_in[10];
    const float* prev_link       = (const float*)d_in[11];
    const float* prev_prec       = (const float*)d_in[12];

    float* out = (float*)d_out;
    float* out_rw    = out;                               // [B,R,N]
    float* out_ww    = out_rw + (size_t)B * R * N;        // [B,NW,N]
    float* out_usage = out_ww + (size_t)B * NW * N;       // [B,N]
    float* out_link  = out_usage + (size_t)B * N;         // [B,NW,N,N]
    float* out_prec  = out_link + (size_t)B * NW * N * N; // [B,NW,N]

    dim3 g1(N / 256, B);
    k_prep1<<<g1, 256, 0, stream>>>(memory, read_keys, read_strengths,
                                    write_keys, write_strengths, free_gate,
                                    prev_read_w, prev_write_w, prev_usage,
                                    out_usage, out_rw, out_ww);

    k_allocsmww<<<B, 1024, 0, stream>>>(out_usage, out_rw, out_ww,
                                        alloc_gate, write_gate,
                                        prev_prec, out_prec);

    k_link<<<(B * N) / RPB, 256, 0, stream>>>(out_ww, prev_prec,
                                              prev_link, out_link);
}

// Round 8
// 118.063 us; speedup vs baseline: 1.7502x; 1.0319x over previous
//
#include <hip/hip_runtime.h>
#include <math.h>

#define EPS 1e-5f
#define B 64
#define N 1024
#define W 64
#define R 4
#define NW 1
#define RPB 4   // rows per block in k_link (R6-proven)

typedef float f4 __attribute__((ext_vector_type(4)));

__device__ __forceinline__ float softplus_f(float x) {
    return x > 0.f ? x + log1pf(expf(-x)) : log1pf(expf(x));
}

// Block-wide reduction over 1024 threads (16 waves). sred: 16 floats.
template <bool IS_MAX>
__device__ __forceinline__ float block_reduce(float v, float* sred) {
    #pragma unroll
    for (int off = 32; off >= 1; off >>= 1) {
        float o = __shfl_xor(v, off);
        v = IS_MAX ? fmaxf(v, o) : v + o;
    }
    __syncthreads();                    // protect sred reuse across calls
    if ((threadIdx.x & 63) == 0) sred[threadIdx.x >> 6] = v;
    __syncthreads();
    float r = sred[0];
    #pragma unroll
    for (int i = 1; i < 16; ++i) r = IS_MAX ? fmaxf(r, sred[i]) : r + sred[i];
    return r;
}

// ---- prep1: usage + sharpened cosine acts (one memory pass). grid (4,B)x256
// (verbatim from R7)
__global__ __launch_bounds__(256) void k_prep1(
    const float* __restrict__ memory,
    const float* __restrict__ read_keys,
    const float* __restrict__ read_strengths,
    const float* __restrict__ write_keys,
    const float* __restrict__ write_strengths,
    const float* __restrict__ free_gate,
    const float* __restrict__ prev_read_w,
    const float* __restrict__ prev_write_w,
    const float* __restrict__ prev_usage,
    float* __restrict__ out_usage,
    float* __restrict__ out_rw,    // [B,R,N] sharpened acts (pre-softmax)
    float* __restrict__ out_ww) {  // [B,N]   sharpened acts (pre-softmax)
    __shared__ float sk[5 * W];
    __shared__ float s_knorm[5];
    __shared__ float s_scale[5];
    int b = blockIdx.y;
    int t = threadIdx.x;
    int n = blockIdx.x * 256 + t;

    for (int l = t; l < 5 * W; l += 256) {
        int h = l >> 6, w = l & 63;
        sk[l] = (h < R) ? read_keys[((size_t)b * R + h) * W + w]
                        : write_keys[(size_t)b * W + w];
    }
    __syncthreads();
    if (t < 5) {
        float s = 0.f;
        for (int w = 0; w < W; ++w) s += sk[t * W + w] * sk[t * W + w];
        s_knorm[t] = sqrtf(s + EPS);
        float st = (t < R) ? read_strengths[b * R + t] : write_strengths[b];
        s_scale[t] = softplus_f(st);
    }

    // usage (independent of keys; overlaps the key-norm work)
    float ww = prev_write_w[(size_t)b * N + n];     // NW == 1
    float pun = prev_usage[(size_t)b * N + n];
    float u = pun + (1.f - pun) * ww;
    float phi = 1.f;
    #pragma unroll
    for (int r = 0; r < R; ++r)
        phi *= 1.f - free_gate[b * R + r] * prev_read_w[((size_t)b * R + r) * N + n];
    out_usage[(size_t)b * N + n] = u * phi;

    __syncthreads();

    const f4* mrow = (const f4*)(memory + ((size_t)b * N + n) * W);
    float dot[5] = {0.f, 0.f, 0.f, 0.f, 0.f};
    float msum = 0.f;
    #pragma unroll
    for (int w4 = 0; w4 < W / 4; ++w4) {
        f4 m = mrow[w4];
        msum += m.x * m.x + m.y * m.y + m.z * m.z + m.w * m.w;
        #pragma unroll
        for (int h = 0; h < 5; ++h)
            dot[h] += sk[h * W + w4 * 4 + 0] * m.x + sk[h * W + w4 * 4 + 1] * m.y
                    + sk[h * W + w4 * 4 + 2] * m.z + sk[h * W + w4 * 4 + 3] * m.w;
    }
    float mnorm = sqrtf(msum + EPS);
    #pragma unroll
    for (int h = 0; h < 5; ++h) {
        float sharp = (dot[h] / (s_knorm[h] * mnorm + EPS)) * s_scale[h];
        if (h < R) out_rw[((size_t)b * R + h) * N + n] = sharp;
        else       out_ww[(size_t)b * N + n] = sharp;
    }
}

// ---- alloc (register/shuffle bitonic) + softmax(5) + ww + precedence ----
// One block of 1024 threads per batch; thread t owns position t.
// Sort: descending nu, stable tie-break by ascending original index.
// Stages with j<64 exchange within a wave via __shfl_xor (no LDS/barriers);
// only j in {64,128,256,512} use LDS (2 barriers each).
__global__ __launch_bounds__(1024) void k_allocsmww(
    const float* __restrict__ usage,
    float* __restrict__ out_rw,          // acts in, softmax out
    float* __restrict__ out_ww,          // acts in, final ww out
    const float* __restrict__ alloc_gate,
    const float* __restrict__ write_gate,
    const float* __restrict__ prev_prec,
    float* __restrict__ out_prec) {
    __shared__ float snu[N];
    __shared__ int   sid[N];
    __shared__ float pp[N];              // wave partials, then alloc scatter
    __shared__ float sred[16];
    int b = blockIdx.x;
    int t = threadIdx.x;
    int lane = t & 63, wid = t >> 6;

    float u = EPS + (1.f - EPS) * usage[(size_t)b * N + t];
    float nu = 1.f - u;                  // nonusage
    int   id = t;

    for (int k = 2; k <= N; k <<= 1) {
        for (int j = k >> 1; j > 0; j >>= 1) {
            bool up = ((t & k) == 0);    // j < k so (t&k) == (partner&k)
            float onu; int oid;
            if (j < 64) {
                onu = __shfl_xor(nu, j);
                oid = __shfl_xor(id, j);
            } else {
                snu[t] = nu; sid[t] = id;
                __syncthreads();
                onu = snu[t ^ j]; oid = sid[t ^ j];
                __syncthreads();
            }
            bool lower = (t & j) == 0;   // am I the lower position of the pair?
            float anu = lower ? nu : onu;  int aid = lower ? id : oid;
            float bnu = lower ? onu : nu;  int bid = lower ? oid : id;
            (void)bid;
            bool a_first = (anu > bnu) || (anu == bnu && aid < bid);
            bool doSwap = up ? !a_first : a_first;
            if (doSwap) { nu = onu; id = oid; }
        }
    }

    // prefix product of sorted usage su = 1 - nu, via wave shuffle-scan
    float su = 1.f - nu;
    float scan = su;                     // wave-inclusive scan
    #pragma unroll
    for (int d = 1; d < 64; d <<= 1) {
        float v = __shfl_up(scan, d, 64);
        if (lane >= d) scan *= v;
    }
    if (lane == 63) pp[wid] = scan;      // wave totals in pp[0..15]
    __syncthreads();
    float wpre = 1.f;                    // product of preceding waves' totals
    #pragma unroll
    for (int i = 0; i < 16; ++i) {
        float pv = pp[i];
        wpre *= (i < wid) ? pv : 1.f;
    }
    __syncthreads();                     // done reading pp; reuse for scatter
    float sc1 = __shfl_up(scan, 1, 64);
    float excl = (lane == 0) ? wpre : sc1 * wpre;   // exclusive prefix product
    pp[id] = nu * excl;                  // scatter sorted_alloc to original slot
    __syncthreads();
    float alloc_t = pp[t];

    // softmax per head (block-wide shuffle+LDS reduce)
    float content = 0.f;
    #pragma unroll
    for (int h = 0; h < 5; ++h) {
        float a = (h < R) ? out_rw[((size_t)b * R + h) * N + t]
                          : out_ww[(size_t)b * N + t];
        float mx = block_reduce<true>(a, sred);
        float e = expf(a - mx);
        float sm = block_reduce<false>(e, sred);
        float p = e / sm;
        if (h < R) out_rw[((size_t)b * R + h) * N + t] = p;
        else       content = p;
    }

    // final write weights + precedence
    float ag = alloc_gate[b], wg = write_gate[b];
    float w = wg * (ag * alloc_t + (1.f - ag) * content);
    float wsum = block_reduce<false>(w, sred);
    out_ww[(size_t)b * N + t] = w;
    out_prec[(size_t)b * N + t] = (1.f - wsum) * prev_prec[(size_t)b * N + t] + w;
}

// ---- link update: RPB=4 rows/block + nontemporal streams (verbatim R7) ----
__global__ void k_link(const float* __restrict__ ww,
                       const float* __restrict__ pprec,
                       const float* __restrict__ plink,
                       float* __restrict__ link) {
    int row0 = blockIdx.x * RPB;        // 1024 % RPB == 0 -> one batch per block
    int b = row0 >> 10;
    int t = threadIdx.x;                // j-chunk: j in [4t, 4t+4)

    f4 wj = ((const f4*)(ww + (size_t)b * N))[t];
    f4 pj = ((const f4*)(pprec + (size_t)b * N))[t];

    float wi[RPB];
    f4    pl[RPB];
    #pragma unroll
    for (int r = 0; r < RPB; ++r) {
        int row = row0 + r;
        wi[r] = ww[row];
        pl[r] = __builtin_nontemporal_load((const f4*)plink + (((size_t)row) << 8) + t);
    }

    #pragma unroll
    for (int r = 0; r < RPB; ++r) {
        int row = row0 + r;
        int i = row & (N - 1);
        f4 a = (1.f - wi[r]) - wj;
        f4 o = a * pl[r] + wi[r] * pj;
        if ((i >> 2) == t) {            // zero the diagonal element
            int jj = i & 3;
            if      (jj == 0) o.x = 0.f;
            else if (jj == 1) o.y = 0.f;
            else if (jj == 2) o.z = 0.f;
            else              o.w = 0.f;
        }
        __builtin_nontemporal_store(o, (f4*)link + (((size_t)row) << 8) + t);
    }
}

extern "C" void kernel_launch(void* const* d_in, const int* in_sizes, int n_in,
                              void* d_out, int out_size, void* d_ws, size_t ws_size,
                              hipStream_t stream) {
    const float* memory          = (const float*)d_in[0];
    const float* read_keys       = (const float*)d_in[1];
    const float* read_strengths  = (const float*)d_in[2];
    const float* write_keys      = (const float*)d_in[3];
    const float* write_strengths = (const float*)d_in[4];
    const float* free_gate       = (const float*)d_in[5];
    const float* alloc_gate      = (const float*)d_in[6];
    const float* write_gate      = (const float*)d_in[7];
    const float* prev_read_w     = (const float*)d_in[8];
    const float* prev_write_w    = (const float*)d_in[9];
    const float* prev_usage      = (const float*)d_in[10];
    const float* prev_link       = (const float*)d_in[11];
    const float* prev_prec       = (const float*)d_in[12];

    float* out = (float*)d_out;
    float* out_rw    = out;                               // [B,R,N]
    float* out_ww    = out_rw + (size_t)B * R * N;        // [B,NW,N]
    float* out_usage = out_ww + (size_t)B * NW * N;       // [B,N]
    float* out_link  = out_usage + (size_t)B * N;         // [B,NW,N,N]
    float* out_prec  = out_link + (size_t)B * NW * N * N; // [B,NW,N]

    dim3 g1(N / 256, B);
    k_prep1<<<g1, 256, 0, stream>>>(memory, read_keys, read_strengths,
                                    write_keys, write_strengths, free_gate,
                                    prev_read_w, prev_write_w, prev_usage,
                                    out_usage, out_rw, out_ww);

    k_allocsmww<<<B, 1024, 0, stream>>>(out_usage, out_rw, out_ww,
                                        alloc_gate, write_gate,
                                        prev_prec, out_prec);

    k_link<<<(B * N) / RPB, 256, 0, stream>>>(out_ww, prev_prec,
                                              prev_link, out_link);
}